// Round 4
// baseline (156.916 us; speedup 1.0000x reference)
//
#include <hip/hip_runtime.h>

// CTC loss forward DP (Keras ctc_batch_cost), mean over batch.
// B=512, T=512, C=96 (blank=95), L=64. One wave per example; lane i owns
// extended states 2i (blank) and 2i+1 (label i); lane 63 also owns state 128.
//
// R4: linear-prob DP (R2 semantics restored). Renorm = wave-max of the
// POST-chunk state -> ldexp to 2^96 (R3's chunk-start deferred renorm let the
// stored max drift to ~2^24 and flushed readout states -> inf). Init scaled
// by 2^96 for uniform margins. FMA-slimmed step (dpp -> fma, ~12 cy chain).
// 8-deep emission ring: per-wave outstanding gathers ride the vmcnt~63 issue
// cap = max legal memory pipelining for a single wave.

#define B_ 512
#define T_ 512
#define C_ 96
#define L_ 64
#define BLANK_ 95
#define EPSF 1e-7f
#define LN2F 0.69314718055994530942f

template <int CTRL>
__device__ __forceinline__ float dpp_mov(float x) {
    // bound_ctrl=true: invalid source lanes read 0 (identity for max of
    // non-negative probs; exactly the "state -1 absent" boundary for shr:1).
    return __int_as_float(
        __builtin_amdgcn_update_dpp(0, __float_as_int(x), CTRL, 0xF, 0xF, true));
}

// Full-wave max (64 lanes), all-VALU; full reduction lands in lane 63.
__device__ __forceinline__ float wave_max(float m) {
    m = fmaxf(m, dpp_mov<0x111>(m));  // row_shr:1
    m = fmaxf(m, dpp_mov<0x112>(m));  // row_shr:2
    m = fmaxf(m, dpp_mov<0x114>(m));  // row_shr:4
    m = fmaxf(m, dpp_mov<0x118>(m));  // row_shr:8
    m = fmaxf(m, dpp_mov<0x142>(m));  // row_bcast:15
    m = fmaxf(m, dpp_mov<0x143>(m));  // row_bcast:31
    return __int_as_float(__builtin_amdgcn_readlane(__float_as_int(m), 63));
}

__launch_bounds__(64, 1)
__global__ void ctc_loss_kernel(const int* __restrict__ y_true,
                                const float* __restrict__ y_pred,
                                float* __restrict__ out) {
    const int b = blockIdx.x;
    const int lane = threadIdx.x;  // 0..63

    // ---- label metadata ----
    const int yv = y_true[b * L_ + lane];
    const unsigned long long act = __ballot(yv != -1);
    const int len = __popcll(act);        // label length (32..64)
    const int lab = (yv == -1) ? 0 : yv;  // padded like the reference
    const int lab_prev = __shfl_up(lab, 1);
    const bool cs = (lane == 0) ? true : (lab != lab_prev);

    const float* rowp = y_pred + (size_t)b * T_ * C_;
    const float* plp = rowp + lab;     // my label's column (per-lane gather)
    const float* pbp = rowp + BLANK_;  // blank column (wave-uniform address)

    // ---- emission prefetch ring: 8 chunks x 8 steps ----
    constexpr int U = 8;
    constexpr int D = 8;
    constexpr int NCH = T_ / U;  // 64
    float bl[D][U], bb[D][U];
#pragma unroll
    for (int d = 0; d < D; ++d)
#pragma unroll
        for (int k = 0; k < U; ++k) {
            bl[d][k] = plp[(d * U + k) * C_];
            bb[d][k] = pbp[(d * U + k) * C_];
        }

    // ---- state (linear space, scaled by 2^-accum); init pre-scaled to 2^96 ----
    float a_even, a_odd, a128;
    int accum = -96;  // true_alpha = stored * 2^accum
    a_even = (lane == 0) ? ldexpf(bb[0][0] + EPSF, 96) : 0.0f;  // state 0
    a_odd  = (lane == 0) ? ldexpf(bl[0][0] + EPSF, 96) : 0.0f;  // state 1
    a128 = 0.0f;                                                // state 128

    // One chunk: off-chain coef precompute, 8 FMA steps, POST-chunk renorm.
    auto chunk_exec = [&](const float* cl, const float* cb, int kstart) {
        float pl[U], pb[U], mpl[U];
#pragma unroll
        for (int k = 0; k < U; ++k) {
            pl[k] = cl[k] + EPSF;
            pb[k] = cb[k] + EPSF;
            mpl[k] = cs ? pl[k] : 0.0f;
        }
#pragma unroll
        for (int k = 0; k < U; ++k) {
            if (k < kstart) continue;
            const float po = dpp_mov<0x138>(a_odd);  // wave_shr:1 -> alpha[2*lane-1]
            const float ne = fmaf(po, pb[k], a_even * pb[k]);
            const float no = fmaf(po, mpl[k], (a_odd + a_even) * pl[k]);
            a128 = fmaf(a_odd, pb[k], a128 * pb[k]);  // meaningful on lane 63
            a_even = ne;
            a_odd = no;
        }
        // renorm from the CURRENT (post-chunk) state -> max into (2^95, 2^96]
        const float mv = wave_max(fmaxf(fmaxf(a_even, a_odd), a128));
        const int e = ((__float_as_int(mv) >> 23) & 0xFF) - 126;
        const int kk = 96 - e;
        a_even = ldexpf(a_even, kk);
        a_odd  = ldexpf(a_odd, kk);
        a128   = ldexpf(a128, kk);
        accum -= kk;
    };

    auto prefetch = [&](float* dl, float* db, int t0) {
#pragma unroll
        for (int k = 0; k < U; ++k) {
            dl[k] = plp[(t0 + k) * C_];
            db[k] = pbp[(t0 + k) * C_];
        }
    };

    // ---- peeled group 0: chunks 0..7 in slots 0..7 ----
#pragma unroll
    for (int sub = 0; sub < D; ++sub) {
        chunk_exec(bl[sub], bb[sub], (sub == 0) ? 1 : 0);
        prefetch(bl[sub], bb[sub], (sub + D) * U);
    }

    // ---- groups 1..7: chunks 8g..8g+7 ----
    for (int g = 1; g < NCH / D; ++g) {
#pragma unroll
        for (int sub = 0; sub < D; ++sub) {
            const int c = g * D + sub;
            chunk_exec(bl[sub], bb[sub], 0);
            if (c + D < NCH) prefetch(bl[sub], bb[sub], (c + D) * U);
        }
    }

    // ---- readout: loss = -ln2 * (log2(a[2len] + a[2len-1]) + accum) ----
    const float al = __shfl(a_odd, len - 1);           // state 2len-1
    const float ab = (len < L_) ? __shfl(a_even, len)  // state 2len
                                : __shfl(a128, 63);    // state 128
    if (lane == 0) {
        const float loss = -LN2F * (log2f(ab + al) + (float)accum);
        atomicAdd(out, loss * (1.0f / B_));
    }
}

extern "C" void kernel_launch(void* const* d_in, const int* in_sizes, int n_in,
                              void* d_out, int out_size, void* d_ws, size_t ws_size,
                              hipStream_t stream) {
    const int* y_true = (const int*)d_in[0];
    const float* y_pred = (const float*)d_in[1];
    float* out = (float*)d_out;
    hipMemsetAsync(out, 0, sizeof(float), stream);
    ctc_loss_kernel<<<B_, 64, 0, stream>>>(y_true, y_pred, out);
}